// Round 11
// baseline (200.614 us; speedup 1.0000x reference)
//
#include <hip/hip_runtime.h>

// RelatEntAtt: E=4096, R=64, D=256. Fully fused recompute; att (E,R,D) never
// materialized. exp2 with log2(e) folded into the adj-softmax output.
// R2 (180.9us): CH=8, JT=16, arrays SROA to regs. Grid 512 -> 18% occ.
// R3/R4 (FAILED): CH=4 breaks SROA (~470 MB scratch traffic). CH=8 + JT=16
//     private-array shapes are load-bearing. DO NOT TOUCH.
// R5/R6/R11 (181/170/167.1us PASSED): j-quarter split, grid 2048.
// R7/R8/R9: fusion attempts foreclosed (cooperative launch incompatible;
//     no spins; atomics only consumable across kernel boundaries).
// R10 (FAILED): bisection reduce -> register cliff. row16_sum load-bearing.
// R12 (170.1us): adj-prologue fold = net loss (+7us in each of kA/kB vs -8us
//     k_adj). Reverted. BUT its profile exposed kA: 67us @ VALUBusy 20%, and
//     WRITE_SIZE == atomic-lane-ops x 4B in BOTH kA (48MB) and kB (49MB),
//     dur ~= WRITE/1TB/s. MODEL: device-scope fp32 atomics execute past the
//     non-coherent per-XCD L2s at the coherence point -> HBM-class write per
//     lane-op @ ~1TB/s. Both hot kernels are ATOMIC-THROUGHPUT-BOUND.
// R13: halve atomic lane-ops. Each block takes SLAB=4 e-chunks (32 e's,
//     grid 512 = 4q x 128 slabs); j-indexed accumulators (lEacc, rAcc) are
//     kept in registers ACROSS the slab and flushed once per block:
//     lE 8.4M->2.1M, racc 8.4M->2.1M lane-ops. Per-e accumulators (lR, sE)
//     still flush per chunk (bigger arrays = R10's register cliff).
//     Inner chunk bodies R11-VERBATIM; slab loop not unrolled.

#define EN 4096
#define RN 64
#define DN 256
#define JT 16          // j-tile width (PROVEN SROA shape - do not change)
#define LOG2E 1.44269504088896340736f
#define CHA 8   // e's per chunk (PROVEN SROA shape - do not change)
#define CHB 8
#define SLAB 4                         // e-chunks per block
#define GRIDS ((EN/(CHA*SLAB))*4)      // 512 blocks: (slab, j-quarter)
#define ZERO_F4 ((RN*DN*2 + EN*DN*2)/4)   // float4 count of zeroed ws region

__device__ __forceinline__ float ex2(float x){ return __builtin_amdgcn_exp2f(x); }
__device__ __forceinline__ float rcpf(float x){ return __builtin_amdgcn_rcpf(x); }

template<int CTRL>
__device__ __forceinline__ float dpp_add(float v){
  int m = __builtin_amdgcn_update_dpp(0, __float_as_int(v), CTRL, 0xf, 0xf, true);
  return v + __int_as_float(m);
}
// lane (i%16)==15 ends with the sum of its 16-lane row
__device__ __forceinline__ float row16_sum(float v){
  v = dpp_add<0x111>(v);
  v = dpp_add<0x112>(v);
  v = dpp_add<0x114>(v);
  v = dpp_add<0x118>(v);
  return v;
}

// ---- s2[e,j] = softmax_j(adj[e,:]) * LOG2E;  also zeroes accumulator ws ----
__global__ __launch_bounds__(256) void k_adj(const float* __restrict__ adj,
                                             float* __restrict__ s2,
                                             float4* __restrict__ zbase){
  const int tid = threadIdx.x;
  const int gt  = blockIdx.x*256 + tid;          // grid 1024 -> 262144 threads
  for(int i = gt; i < ZERO_F4; i += (EN/4)*256)
    zbase[i] = make_float4(0.f, 0.f, 0.f, 0.f);
  const int lane = tid & 63;
  const int e = blockIdx.x*4 + (tid >> 6);
  float a = adj[e*RN + lane];
  float ev = ex2(a * LOG2E);
  float s = ev;
  #pragma unroll
  for(int off = 32; off > 0; off >>= 1) s += __shfl_xor(s, off, 64);
  s2[e*RN + lane] = ev * (LOG2E * rcpf(s));
}

// ---- kA: lRg[e,d] += sum_(own j) ev (per chunk);  lE[j,d] += ev (ONCE) ----
// block = (slab, j-quarter): e00 = (bid>>2)*32, j0 = (bid&3)*16
__global__ __launch_bounds__(256,4) void kA(const float* __restrict__ h,
                                            const float* __restrict__ r,
                                            const float* __restrict__ s2,
                                            float* __restrict__ lRg,
                                            float* __restrict__ lE){
  const int d   = threadIdx.x;
  const int e00 = (blockIdx.x >> 2) * (CHA*SLAB);
  const int j0  = (blockIdx.x & 3) * JT;
  __shared__ float s2s[SLAB*CHA*JT];       // 2 KB: 32 rows x own quarter
  #pragma unroll
  for(int k = 0; k < SLAB*CHA*JT/256; k++){
    const int idx = k*256 + d;             // idx = row*16 + jj
    s2s[idx] = s2[(e00 + (idx >> 4))*RN + j0 + (idx & 15)];
  }
  __syncthreads();

  float rcol[JT], lEacc[JT];
  #pragma unroll
  for(int jj = 0; jj < JT; jj++){ rcol[jj] = r[(j0+jj)*DN + d]; lEacc[jj] = 0.f; }

  for(int sc = 0; sc < SLAB; sc++){        // NOT unrolled (code size, I-cache)
    const int e0 = e00 + sc*CHA;
    float lR[CHA];
    #pragma unroll
    for(int ee = 0; ee < CHA; ee++) lR[ee] = 0.f;
    #pragma unroll
    for(int ee = 0; ee < CHA; ee++){
      const float he = h[(e0+ee)*DN + d];
      #pragma unroll
      for(int jj = 0; jj < JT; jj++){
        float t  = s2s[(sc*CHA+ee)*JT + jj] * he * rcol[jj];
        float ev = ex2(fmaxf(t, 0.2f*t));
        lR[ee]   += ev;
        lEacc[jj] += ev;
      }
    }
    #pragma unroll
    for(int ee = 0; ee < CHA; ee++) atomicAdd(&lRg[(e0+ee)*DN + d], lR[ee]);
  }
  #pragma unroll
  for(int jj = 0; jj < JT; jj++) atomicAdd(&lE[(j0+jj)*DN + d], lEacc[jj]);
}

// ---- kB: main fused sweep, slab of 4 e-chunks ----
// per (e,d): pR = ev/lRg (att_R), pE = ev/lE (att_E)
//   sEg[e,d] += sum_(own j) pE      (atomics, per chunk)
//   r'[j,d] += pR                   rAcc[16] across WHOLE slab, ONE flush
//   alog[e,j] = sum_d pR*W_d        row16 DPP + LDS combine (per chunk)
__global__ __launch_bounds__(256,4) void kB(const float* __restrict__ h,
                                            const float* __restrict__ r,
                                            const float* __restrict__ s2,
                                            const float* __restrict__ lRg,
                                            const float* __restrict__ lE,
                                            const float* __restrict__ W,
                                            float* __restrict__ alog,
                                            float* __restrict__ racc_g,
                                            float* __restrict__ sEg){
  const int tid  = threadIdx.x;            // = d
  const int lane = tid & 63;
  const int grp  = tid >> 4;               // 16 groups of 16 lanes
  const int e00  = (blockIdx.x >> 2) * (CHB*SLAB);
  const int j0   = (blockIdx.x & 3) * JT;
  __shared__ float s2s[SLAB*CHB*JT];       // 2 KB
  __shared__ float apart[CHB*16*20];       // 10 KB, reused per chunk
  #pragma unroll
  for(int k = 0; k < SLAB*CHB*JT/256; k++){
    const int idx = k*256 + tid;
    s2s[idx] = s2[(e00 + (idx >> 4))*RN + j0 + (idx & 15)];
  }
  __syncthreads();

  const float wd = W[tid];
  float rcol[JT], ile[JT], rAcc[JT];
  #pragma unroll
  for(int jj = 0; jj < JT; jj++){
    const int j = j0 + jj;
    rcol[jj] = r[j*DN + tid];
    ile[jj]  = rcpf(lE[j*DN + tid]);
    rAcc[jj] = 0.f;
  }

  for(int sc = 0; sc < SLAB; sc++){        // NOT unrolled
    const int e0 = e00 + sc*CHB;
    float sE[CHB];
    #pragma unroll
    for(int ee = 0; ee < CHB; ee++) sE[ee] = 0.f;
    for(int ee = 0; ee < CHB; ee++){
      const int e = e0 + ee;
      const float he = h[e*DN + tid];
      const float il = rcpf(lRg[e*DN + tid]);
      const float u  = il * wd;
      #pragma unroll
      for(int jg = 0; jg < JT/4; jg++){
        float4 st;
        #pragma unroll
        for(int jj4 = 0; jj4 < 4; jj4++){
          const int jj = jg*4 + jj4;
          float t  = s2s[(sc*CHB+ee)*JT + jj] * he * rcol[jj];
          float ev = ex2(fmaxf(t, 0.2f*t));
          rAcc[jj] = fmaf(ev, il, rAcc[jj]);      // pR accumulated over SLAB e's
          sE[ee]   = fmaf(ev, ile[jj], sE[ee]);   // pE sum over own j
          float rs = row16_sum(ev * u);           // alog contribution
          if(jj4==0) st.x = rs; else if(jj4==1) st.y = rs;
          else if(jj4==2) st.z = rs; else st.w = rs;
        }
        if((lane & 15) == 15){
          *reinterpret_cast<float4*>(&apart[(ee*16 + grp)*20 + jg*4]) = st;
        }
      }
    }
    __syncthreads();
    if(tid < CHB*JT){                      // 128 threads: ee = tid>>4, jj = tid&15
      const int ee = tid >> 4, jj = tid & 15;
      float sum = 0.f;
      #pragma unroll
      for(int g = 0; g < 16; g++) sum += apart[(ee*16 + g)*20 + jj];
      alog[(e0+ee)*RN + j0 + jj] = sum;
    }
    #pragma unroll
    for(int ee = 0; ee < CHB; ee++) atomicAdd(&sEg[(e0+ee)*DN + tid], sE[ee]);
    __syncthreads();                       // protect apart before next chunk
  }
  #pragma unroll
  for(int jj = 0; jj < JT; jj++) atomicAdd(&racc_g[(j0+jj)*DN + tid], rAcc[jj]);
}

// ---- tail: hout = elu(h*sEg) everywhere; blocks 0..63 also do rout + alpha ----
// (reference's reshape(R,E,1)+softmax(axis=1) == per-row softmax on the e*64+j
//  flat array viewed as [64][4096]; b_lin dropped by shift invariance)
__global__ __launch_bounds__(256) void kTail(const float* __restrict__ h,
                                             const float* __restrict__ sEg,
                                             const float* __restrict__ alog,
                                             const float* __restrict__ r,
                                             const float* __restrict__ racc,
                                             float* __restrict__ hout,
                                             float* __restrict__ rout,
                                             float* __restrict__ aout){
  const int b = blockIdx.x, tid = threadIdx.x;
  {
    const int i = b*256 + tid;               // grid 4096 covers EN*DN
    float hp = h[i] * sEg[i];
    hout[i] = hp > 0.f ? hp : (ex2(hp*LOG2E) - 1.0f);
  }
  if(b < RN){                                 // block-uniform branch
    const int i = b*DN + tid;
    float v = r[i] * racc[i];
    rout[i] = v > 0.f ? v : (ex2(v*LOG2E) - 1.0f);

    const float* __restrict__ row = alog + b*EN;
    float exv[16]; float s = 0.f;
    #pragma unroll
    for(int k = 0; k < 16; k++){
      float v2 = ex2(row[k*256 + tid] * LOG2E);
      exv[k] = v2; s += v2;
    }
    #pragma unroll
    for(int off = 32; off > 0; off >>= 1) s += __shfl_xor(s, off, 64);
    __shared__ float wsum[4];
    if((tid & 63) == 0) wsum[tid>>6] = s;
    __syncthreads();
    float inv = 1.0f / (wsum[0] + wsum[1] + wsum[2] + wsum[3]);
    float* __restrict__ orow = aout + b*EN;
    #pragma unroll
    for(int k = 0; k < 16; k++) orow[k*256 + tid] = exv[k] * inv;
  }
}

extern "C" void kernel_launch(void* const* d_in, const int* in_sizes, int n_in,
                              void* d_out, int out_size, void* d_ws, size_t ws_size,
                              hipStream_t stream){
  (void)in_sizes; (void)n_in; (void)out_size; (void)ws_size;
  const float* h   = (const float*)d_in[0];
  const float* r   = (const float*)d_in[1];
  const float* adj = (const float*)d_in[2];
  const float* W   = (const float*)d_in[3];
  // d_in[4] = b_lin: unused (softmax shift invariance)

  float* ws   = (float*)d_ws;
  float* s2   = ws;                  // EN*RN
  float* lE   = s2 + EN*RN;          // RN*DN  --+
  float* racc = lE + RN*DN;          // RN*DN    | zeroed by k_adj
  float* lRg  = racc + RN*DN;        // EN*DN    |
  float* sEg  = lRg + EN*DN;         // EN*DN  --+
  float* alog = sEg + EN*DN;         // EN*RN

  float* hout = (float*)d_out;           // EN*DN
  float* rout = hout + EN*DN;            // RN*DN
  float* aout = rout + RN*DN;            // RN*EN

  k_adj<<<EN/4,      256, 0, stream>>>(adj, s2, (float4*)lE);
  kA   <<<GRIDS,     256, 0, stream>>>(h, r, s2, lRg, lE);
  kB   <<<GRIDS,     256, 0, stream>>>(h, r, s2, lRg, lE, W, alog, racc, sEg);
  kTail<<<EN*DN/256, 256, 0, stream>>>(h, sEg, alog, r, racc, hout, rout, aout);
}

// Round 12
// 168.792 us; speedup vs baseline: 1.1885x; 1.1885x over previous
//
#include <hip/hip_runtime.h>

// RelatEntAtt: E=4096, R=64, D=256. Fully fused recompute; att (E,R,D) never
// materialized. exp2 with log2(e) folded into the adj-softmax output.
// ---- session ledger ----
// R2 (180.9us): CH=8, JT=16, arrays SROA to regs. Grid 512 -> 18% occ.
// R3/R4 (FAILED): CH=4 breaks SROA (~470 MB scratch). CH=8 + JT=16 private-
//     array shapes are load-bearing. DO NOT TOUCH.
// R5 (181us): j-half split, grid 1024. SROA held -> orchestration edits safe.
// R6/R11 (170.1/167.1us PASSED, BEST): j-quarter split, grid 2048. kB 58.5us,
//     VALUBusy 67%, FETCH 17.6MB, occ 33%.
// R7 (FAILED): hipLaunchCooperativeKernel incompatible with harness capture.
// R8 (FAILED): spin grid-barrier -> likely deadlock. NO SPINS.
// R9 (FAILED): intra-kernel consumption of remote-XCD atomics unsafe; atomic
//     results only consumable across a kernel boundary.
// R10 (FAILED): bisection reduce -> register cliff (FETCH 182MB). row16_sum's
//     immediate-consume DPP scan is register-minimal and load-bearing.
// R12 (170.1us): adj-fold into kA/kB = net loss; reverted. Profile suggested
//     both kernels ~atomic-write-throughput-bound (WRITE ~= lane-ops x 4B,
//     dur ~= WRITE / ~1TB/s).
// R13 (FAILED, 200us): SLAB=4 slab-accumulation to halve atomics -> SROA
//     cliff AGAIN (kA WRITE 132MB, scratch despite 64 VGPR used / 128 avail).
//     4th confirmation: any added cross-loop live state breaks codegen.
// R14: R11 VERBATIM — the verified optimum. Structural floor ~165us for this
//     4-dispatch decomposition; the binding constraints are compiler SROA
//     fragility, harness launch restrictions, and cross-XCD atomic visibility,
//     not a hardware pipe.

#define EN 4096
#define RN 64
#define DN 256
#define JT 16          // j-tile width (PROVEN SROA shape - do not change)
#define LOG2E 1.44269504088896340736f
#define CHA 8   // e's per block in kA (PROVEN SROA shape - do not change)
#define CHB 8   // e's per block in kB (PROVEN SROA shape - do not change)
#define ZERO_F4 ((RN*DN*2 + EN*DN*2)/4)   // float4 count of zeroed ws region

__device__ __forceinline__ float ex2(float x){ return __builtin_amdgcn_exp2f(x); }
__device__ __forceinline__ float rcpf(float x){ return __builtin_amdgcn_rcpf(x); }

template<int CTRL>
__device__ __forceinline__ float dpp_add(float v){
  int m = __builtin_amdgcn_update_dpp(0, __float_as_int(v), CTRL, 0xf, 0xf, true);
  return v + __int_as_float(m);
}
// lane (i%16)==15 ends with the sum of its 16-lane row
__device__ __forceinline__ float row16_sum(float v){
  v = dpp_add<0x111>(v);
  v = dpp_add<0x112>(v);
  v = dpp_add<0x114>(v);
  v = dpp_add<0x118>(v);
  return v;
}

// ---- s2[e,j] = softmax_j(adj[e,:]) * LOG2E;  also zeroes accumulator ws ----
__global__ __launch_bounds__(256) void k_adj(const float* __restrict__ adj,
                                             float* __restrict__ s2,
                                             float4* __restrict__ zbase){
  const int tid = threadIdx.x;
  const int gt  = blockIdx.x*256 + tid;          // grid 1024 -> 262144 threads
  for(int i = gt; i < ZERO_F4; i += (EN/4)*256)
    zbase[i] = make_float4(0.f, 0.f, 0.f, 0.f);
  const int lane = tid & 63;
  const int e = blockIdx.x*4 + (tid >> 6);
  float a = adj[e*RN + lane];
  float ev = ex2(a * LOG2E);
  float s = ev;
  #pragma unroll
  for(int off = 32; off > 0; off >>= 1) s += __shfl_xor(s, off, 64);
  s2[e*RN + lane] = ev * (LOG2E * rcpf(s));
}

// ---- kA: lRg[e,d] += sum_(own j) ev;  lE[j,d] += ev ----
// block = (e-chunk, j-quarter): e0 = (bid>>2)*CHA, j0 = (bid&3)*16
__global__ __launch_bounds__(256,4) void kA(const float* __restrict__ h,
                                            const float* __restrict__ r,
                                            const float* __restrict__ s2,
                                            float* __restrict__ lRg,
                                            float* __restrict__ lE){
  const int d  = threadIdx.x;
  const int e0 = (blockIdx.x >> 2) * CHA;
  const int j0 = (blockIdx.x & 3) * JT;
  __shared__ float s2s[CHA*JT];            // 512 B
  if(d < CHA*JT) s2s[d] = s2[(e0 + (d >> 4))*RN + j0 + (d & 15)];
  __syncthreads();

  float lR[CHA];
  #pragma unroll
  for(int ee = 0; ee < CHA; ee++) lR[ee] = 0.f;

  float rcol[JT], lEacc[JT];
  #pragma unroll
  for(int jj = 0; jj < JT; jj++){ rcol[jj] = r[(j0+jj)*DN + d]; lEacc[jj] = 0.f; }
  #pragma unroll
  for(int ee = 0; ee < CHA; ee++){
    const float he = h[(e0+ee)*DN + d];
    #pragma unroll
    for(int jj = 0; jj < JT; jj++){
      float t  = s2s[ee*JT + jj] * he * rcol[jj];
      float ev = ex2(fmaxf(t, 0.2f*t));
      lR[ee]   += ev;
      lEacc[jj] += ev;
    }
  }
  #pragma unroll
  for(int jj = 0; jj < JT; jj++) atomicAdd(&lE[(j0+jj)*DN + d], lEacc[jj]);
  #pragma unroll
  for(int ee = 0; ee < CHA; ee++) atomicAdd(&lRg[(e0+ee)*DN + d], lR[ee]);
}

// ---- kB: main fused sweep over own j-quarter ----
// per (e,d): pR = ev/lRg (att_R), pE = ev/lE (att_E)
//   sEg[e,d] += sum_(own j) pE      (atomics; h' ELU in kTail)
//   r'[j,d] += pR                   16-reg acc, atomic flush
//   alog[e,j] = sum_d pR*W_d        row16 DPP + LDS partial combine (j owned)
__global__ __launch_bounds__(256,4) void kB(const float* __restrict__ h,
                                            const float* __restrict__ r,
                                            const float* __restrict__ s2,
                                            const float* __restrict__ lRg,
                                            const float* __restrict__ lE,
                                            const float* __restrict__ W,
                                            float* __restrict__ alog,
                                            float* __restrict__ racc_g,
                                            float* __restrict__ sEg){
  const int tid  = threadIdx.x;            // = d
  const int lane = tid & 63;
  const int grp  = tid >> 4;               // 16 groups of 16 lanes
  const int e0   = (blockIdx.x >> 2) * CHB;
  const int j0   = (blockIdx.x & 3) * JT;
  __shared__ float s2s[CHB*JT];            // 512 B
  __shared__ float apart[CHB*16*20];       // [ee][g][jj], jj stride 1, g stride 20 -> 10 KB
  if(tid < CHB*JT) s2s[tid] = s2[(e0 + (tid >> 4))*RN + j0 + (tid & 15)];
  __syncthreads();

  const float wd = W[tid];
  float sE[CHB];
  #pragma unroll
  for(int ee = 0; ee < CHB; ee++) sE[ee] = 0.f;

  float rcol[JT], ile[JT], rAcc[JT];
  #pragma unroll
  for(int jj = 0; jj < JT; jj++){
    const int j = j0 + jj;
    rcol[jj] = r[j*DN + tid];
    ile[jj]  = rcpf(lE[j*DN + tid]);
    rAcc[jj] = 0.f;
  }
  for(int ee = 0; ee < CHB; ee++){
    const int e = e0 + ee;
    const float he = h[e*DN + tid];
    const float il = rcpf(lRg[e*DN + tid]);
    const float u  = il * wd;
    #pragma unroll
    for(int jg = 0; jg < JT/4; jg++){
      float4 st;
      #pragma unroll
      for(int jj4 = 0; jj4 < 4; jj4++){
        const int jj = jg*4 + jj4;
        float t  = s2s[ee*JT + jj] * he * rcol[jj];
        float ev = ex2(fmaxf(t, 0.2f*t));
        rAcc[jj] = fmaf(ev, il, rAcc[jj]);      // pR accumulated over e
        sE[ee]   = fmaf(ev, ile[jj], sE[ee]);   // pE sum over own j
        float rs = row16_sum(ev * u);           // alog contribution
        if(jj4==0) st.x = rs; else if(jj4==1) st.y = rs;
        else if(jj4==2) st.z = rs; else st.w = rs;
      }
      if((lane & 15) == 15){
        *reinterpret_cast<float4*>(&apart[(ee*16 + grp)*20 + jg*4]) = st;
      }
    }
  }
  __syncthreads();
  if(tid < CHB*JT){                        // 128 threads: ee = tid>>4, jj = tid&15
    const int ee = tid >> 4, jj = tid & 15;
    float sum = 0.f;
    #pragma unroll
    for(int g = 0; g < 16; g++) sum += apart[(ee*16 + g)*20 + jj];
    alog[(e0+ee)*RN + j0 + jj] = sum;
  }
  #pragma unroll
  for(int jj = 0; jj < JT; jj++) atomicAdd(&racc_g[(j0+jj)*DN + tid], rAcc[jj]);
  #pragma unroll
  for(int ee = 0; ee < CHB; ee++) atomicAdd(&sEg[(e0+ee)*DN + tid], sE[ee]);
}

// ---- tail: hout = elu(h*sEg) everywhere; blocks 0..63 also do rout + alpha ----
// (reference's reshape(R,E,1)+softmax(axis=1) == per-row softmax on the e*64+j
//  flat array viewed as [64][4096]; b_lin dropped by shift invariance)
__global__ __launch_bounds__(256) void kTail(const float* __restrict__ h,
                                             const float* __restrict__ sEg,
                                             const float* __restrict__ alog,
                                             const float* __restrict__ r,
                                             const float* __restrict__ racc,
                                             float* __restrict__ hout,
                                             float* __restrict__ rout,
                                             float* __restrict__ aout){
  const int b = blockIdx.x, tid = threadIdx.x;
  {
    const int i = b*256 + tid;               // grid 4096 covers EN*DN
    float hp = h[i] * sEg[i];
    hout[i] = hp > 0.f ? hp : (ex2(hp*LOG2E) - 1.0f);
  }
  if(b < RN){                                 // block-uniform branch
    const int i = b*DN + tid;
    float v = r[i] * racc[i];
    rout[i] = v > 0.f ? v : (ex2(v*LOG2E) - 1.0f);

    const float* __restrict__ row = alog + b*EN;
    float exv[16]; float s = 0.f;
    #pragma unroll
    for(int k = 0; k < 16; k++){
      float v2 = ex2(row[k*256 + tid] * LOG2E);
      exv[k] = v2; s += v2;
    }
    #pragma unroll
    for(int off = 32; off > 0; off >>= 1) s += __shfl_xor(s, off, 64);
    __shared__ float wsum[4];
    if((tid & 63) == 0) wsum[tid>>6] = s;
    __syncthreads();
    float inv = 1.0f / (wsum[0] + wsum[1] + wsum[2] + wsum[3]);
    float* __restrict__ orow = aout + b*EN;
    #pragma unroll
    for(int k = 0; k < 16; k++) orow[k*256 + tid] = exv[k] * inv;
  }
}

extern "C" void kernel_launch(void* const* d_in, const int* in_sizes, int n_in,
                              void* d_out, int out_size, void* d_ws, size_t ws_size,
                              hipStream_t stream){
  (void)in_sizes; (void)n_in; (void)out_size; (void)ws_size;
  const float* h   = (const float*)d_in[0];
  const float* r   = (const float*)d_in[1];
  const float* adj = (const float*)d_in[2];
  const float* W   = (const float*)d_in[3];
  // d_in[4] = b_lin: unused (softmax shift invariance)

  float* ws   = (float*)d_ws;
  float* s2   = ws;                  // EN*RN
  float* lE   = s2 + EN*RN;          // RN*DN  --+
  float* racc = lE + RN*DN;          // RN*DN    | zeroed by k_adj
  float* lRg  = racc + RN*DN;        // EN*DN    |
  float* sEg  = lRg + EN*DN;         // EN*DN  --+
  float* alog = sEg + EN*DN;         // EN*RN

  float* hout = (float*)d_out;           // EN*DN
  float* rout = hout + EN*DN;            // RN*DN
  float* aout = rout + RN*DN;            // RN*EN

  k_adj<<<EN/4,      256, 0, stream>>>(adj, s2, (float4*)lE);
  kA   <<<EN/CHA*4,  256, 0, stream>>>(h, r, s2, lRg, lE);
  kB   <<<EN/CHB*4,  256, 0, stream>>>(h, r, s2, lRg, lE, W, alog, racc, sEg);
  kTail<<<EN*DN/256, 256, 0, stream>>>(h, sEg, alog, r, racc, hout, rout, aout);
}

// Round 13
// 160.661 us; speedup vs baseline: 1.2487x; 1.0506x over previous
//
#include <hip/hip_runtime.h>

// RelatEntAtt: E=4096, R=64, D=256. Fully fused recompute; att (E,R,D) never
// materialized. exp2 with log2(e) folded into the adj-softmax output.
// ---- session ledger ----
// R2 (180.9us): CH=8, JT=16, arrays SROA to regs.
// R3/R4/R10/R13 (FAILED): ANY change to private-array shapes / cross-loop live
//     state breaks SROA -> scratch (4 confirmations). CH=8 + JT=16 + row16_sum
//     immediate-consume DPP are load-bearing. DO NOT TOUCH HOT LOOPS.
// R5/R6/R11/R14 (181/170.1/167.1/168.8us PASSED): j-quarter split, grid 2048.
//     kB 58us, VALUBusy 67%, FETCH 17.6MB, WRITE 50MB.
// R7/R8/R9 (FAILED): cooperative launch incompatible; no spin barriers; atomic
//     results only consumable across a kernel boundary (cross-XCD visibility).
// R12 (170.1us): adj-fold net loss. Exposed the atomic model: WRITE_SIZE ==
//     atomic-lane-ops x 4B in BOTH kA (48MB) and kB (50MB), ~0.9TB/s drain.
// R15: fanin-4 accumulators (lRg, sEg) -> per-quarter SLICED PLAIN STORES
//     (epilogue-only; hot loops verbatim). Removes 4.2M atomic lane-ops from
//     each hot kernel. lE/racc (fanin 512) stay atomic. ws grows to 35.8MB;
//     launcher falls back to the R14-identical path (template<bool SL>, body
//     written once) if ws_size is insufficient.

#define EN 4096
#define RN 64
#define DN 256
#define JT 16          // j-tile width (PROVEN SROA shape - do not change)
#define LOG2E 1.44269504088896340736f
#define CHA 8   // e's per block (PROVEN SROA shape - do not change)
#define CHB 8
#define GRIDAB ((EN/CHA)*4)            // 2048 blocks: (e-chunk, j-quarter)
#define SZE (EN*DN)                    // slice stride for lRg4/sEg4

__device__ __forceinline__ float ex2(float x){ return __builtin_amdgcn_exp2f(x); }
__device__ __forceinline__ float rcpf(float x){ return __builtin_amdgcn_rcpf(x); }

template<int CTRL>
__device__ __forceinline__ float dpp_add(float v){
  int m = __builtin_amdgcn_update_dpp(0, __float_as_int(v), CTRL, 0xf, 0xf, true);
  return v + __int_as_float(m);
}
// lane (i%16)==15 ends with the sum of its 16-lane row
__device__ __forceinline__ float row16_sum(float v){
  v = dpp_add<0x111>(v);
  v = dpp_add<0x112>(v);
  v = dpp_add<0x114>(v);
  v = dpp_add<0x118>(v);
  return v;
}

// ---- s2[e,j] = softmax_j(adj[e,:]) * LOG2E;  also zeroes accumulator ws ----
__global__ __launch_bounds__(256) void k_adj(const float* __restrict__ adj,
                                             float* __restrict__ s2,
                                             float4* __restrict__ zbase,
                                             int nf4){
  const int tid = threadIdx.x;
  const int gt  = blockIdx.x*256 + tid;          // grid 1024
  for(int i = gt; i < nf4; i += (EN/4)*256)
    zbase[i] = make_float4(0.f, 0.f, 0.f, 0.f);
  const int lane = tid & 63;
  const int e = blockIdx.x*4 + (tid >> 6);
  float a = adj[e*RN + lane];
  float ev = ex2(a * LOG2E);
  float s = ev;
  #pragma unroll
  for(int off = 32; off > 0; off >>= 1) s += __shfl_xor(s, off, 64);
  s2[e*RN + lane] = ev * (LOG2E * rcpf(s));
}

// ---- kA: lRg[e,d] (sliced store or atomic);  lE[j,d] += ev (atomic) ----
// block = (e-chunk, j-quarter): e0 = (bid>>2)*CHA, j0 = (bid&3)*16
template<bool SL>
__global__ __launch_bounds__(256,4) void kA(const float* __restrict__ h,
                                            const float* __restrict__ r,
                                            const float* __restrict__ s2,
                                            float* __restrict__ lRg,
                                            float* __restrict__ lE){
  const int d  = threadIdx.x;
  const int q  = blockIdx.x & 3;
  const int e0 = (blockIdx.x >> 2) * CHA;
  const int j0 = q * JT;
  __shared__ float s2s[CHA*JT];            // 512 B
  if(d < CHA*JT) s2s[d] = s2[(e0 + (d >> 4))*RN + j0 + (d & 15)];
  __syncthreads();

  float lR[CHA];
  #pragma unroll
  for(int ee = 0; ee < CHA; ee++) lR[ee] = 0.f;

  float rcol[JT], lEacc[JT];
  #pragma unroll
  for(int jj = 0; jj < JT; jj++){ rcol[jj] = r[(j0+jj)*DN + d]; lEacc[jj] = 0.f; }
  #pragma unroll
  for(int ee = 0; ee < CHA; ee++){
    const float he = h[(e0+ee)*DN + d];
    #pragma unroll
    for(int jj = 0; jj < JT; jj++){
      float t  = s2s[ee*JT + jj] * he * rcol[jj];
      float ev = ex2(fmaxf(t, 0.2f*t));
      lR[ee]   += ev;
      lEacc[jj] += ev;
    }
  }
  #pragma unroll
  for(int jj = 0; jj < JT; jj++) atomicAdd(&lE[(j0+jj)*DN + d], lEacc[jj]);
  if constexpr(SL){
    #pragma unroll
    for(int ee = 0; ee < CHA; ee++) lRg[q*SZE + (e0+ee)*DN + d] = lR[ee];
  } else {
    #pragma unroll
    for(int ee = 0; ee < CHA; ee++) atomicAdd(&lRg[(e0+ee)*DN + d], lR[ee]);
  }
}

// ---- kB: main fused sweep over own j-quarter ----
// per (e,d): pR = ev/lR (att_R), pE = ev/lE (att_E)
//   sEg[e,d]: sliced store (or atomic)   (h' ELU in kTail)
//   r'[j,d] += pR                        16-reg acc, atomic flush
//   alog[e,j] = sum_d pR*W_d             row16 DPP + LDS partial combine
template<bool SL>
__global__ __launch_bounds__(256,4) void kB(const float* __restrict__ h,
                                            const float* __restrict__ r,
                                            const float* __restrict__ s2,
                                            const float* __restrict__ lRg,
                                            const float* __restrict__ lE,
                                            const float* __restrict__ W,
                                            float* __restrict__ alog,
                                            float* __restrict__ racc_g,
                                            float* __restrict__ sEg){
  const int tid  = threadIdx.x;            // = d
  const int lane = tid & 63;
  const int grp  = tid >> 4;               // 16 groups of 16 lanes
  const int q    = blockIdx.x & 3;
  const int e0   = (blockIdx.x >> 2) * CHB;
  const int j0   = q * JT;
  __shared__ float s2s[CHB*JT];            // 512 B
  __shared__ float apart[CHB*16*20];       // [ee][g][jj], jj stride 1, g stride 20 -> 10 KB
  if(tid < CHB*JT) s2s[tid] = s2[(e0 + (tid >> 4))*RN + j0 + (tid & 15)];
  __syncthreads();

  const float wd = W[tid];
  float sE[CHB];
  #pragma unroll
  for(int ee = 0; ee < CHB; ee++) sE[ee] = 0.f;

  float rcol[JT], ile[JT], rAcc[JT];
  #pragma unroll
  for(int jj = 0; jj < JT; jj++){
    const int j = j0 + jj;
    rcol[jj] = r[j*DN + tid];
    ile[jj]  = rcpf(lE[j*DN + tid]);
    rAcc[jj] = 0.f;
  }
  for(int ee = 0; ee < CHB; ee++){
    const int e = e0 + ee;
    const float he = h[e*DN + tid];
    float il;
    if constexpr(SL){
      const int i = e*DN + tid;
      il = rcpf(lRg[i] + lRg[SZE + i] + lRg[2*SZE + i] + lRg[3*SZE + i]);
    } else {
      il = rcpf(lRg[e*DN + tid]);
    }
    const float u  = il * wd;
    #pragma unroll
    for(int jg = 0; jg < JT/4; jg++){
      float4 st;
      #pragma unroll
      for(int jj4 = 0; jj4 < 4; jj4++){
        const int jj = jg*4 + jj4;
        float t  = s2s[ee*JT + jj] * he * rcol[jj];
        float ev = ex2(fmaxf(t, 0.2f*t));
        rAcc[jj] = fmaf(ev, il, rAcc[jj]);      // pR accumulated over e
        sE[ee]   = fmaf(ev, ile[jj], sE[ee]);   // pE sum over own j
        float rs = row16_sum(ev * u);           // alog contribution
        if(jj4==0) st.x = rs; else if(jj4==1) st.y = rs;
        else if(jj4==2) st.z = rs; else st.w = rs;
      }
      if((lane & 15) == 15){
        *reinterpret_cast<float4*>(&apart[(ee*16 + grp)*20 + jg*4]) = st;
      }
    }
  }
  __syncthreads();
  if(tid < CHB*JT){                        // 128 threads: ee = tid>>4, jj = tid&15
    const int ee = tid >> 4, jj = tid & 15;
    float sum = 0.f;
    #pragma unroll
    for(int g = 0; g < 16; g++) sum += apart[(ee*16 + g)*20 + jj];
    alog[(e0+ee)*RN + j0 + jj] = sum;
  }
  #pragma unroll
  for(int jj = 0; jj < JT; jj++) atomicAdd(&racc_g[(j0+jj)*DN + tid], rAcc[jj]);
  if constexpr(SL){
    #pragma unroll
    for(int ee = 0; ee < CHB; ee++) sEg[q*SZE + (e0+ee)*DN + tid] = sE[ee];
  } else {
    #pragma unroll
    for(int ee = 0; ee < CHB; ee++) atomicAdd(&sEg[(e0+ee)*DN + tid], sE[ee]);
  }
}

// ---- tail: hout = elu(h*sEg) everywhere; blocks 0..63 also do rout + alpha ----
// (reference's reshape(R,E,1)+softmax(axis=1) == per-row softmax on the e*64+j
//  flat array viewed as [64][4096]; b_lin dropped by shift invariance)
template<bool SL>
__global__ __launch_bounds__(256) void kTail(const float* __restrict__ h,
                                             const float* __restrict__ sEg,
                                             const float* __restrict__ alog,
                                             const float* __restrict__ r,
                                             const float* __restrict__ racc,
                                             float* __restrict__ hout,
                                             float* __restrict__ rout,
                                             float* __restrict__ aout){
  const int b = blockIdx.x, tid = threadIdx.x;
  {
    const int i = b*256 + tid;               // grid 4096 covers EN*DN
    float sv;
    if constexpr(SL) sv = sEg[i] + sEg[SZE + i] + sEg[2*SZE + i] + sEg[3*SZE + i];
    else             sv = sEg[i];
    float hp = h[i] * sv;
    hout[i] = hp > 0.f ? hp : (ex2(hp*LOG2E) - 1.0f);
  }
  if(b < RN){                                 // block-uniform branch
    const int i = b*DN + tid;
    float v = r[i] * racc[i];
    rout[i] = v > 0.f ? v : (ex2(v*LOG2E) - 1.0f);

    const float* __restrict__ row = alog + b*EN;
    float exv[16]; float s = 0.f;
    #pragma unroll
    for(int k = 0; k < 16; k++){
      float v2 = ex2(row[k*256 + tid] * LOG2E);
      exv[k] = v2; s += v2;
    }
    #pragma unroll
    for(int off = 32; off > 0; off >>= 1) s += __shfl_xor(s, off, 64);
    __shared__ float wsum[4];
    if((tid & 63) == 0) wsum[tid>>6] = s;
    __syncthreads();
    float inv = 1.0f / (wsum[0] + wsum[1] + wsum[2] + wsum[3]);
    float* __restrict__ orow = aout + b*EN;
    #pragma unroll
    for(int k = 0; k < 16; k++) orow[k*256 + tid] = exv[k] * inv;
  }
}

extern "C" void kernel_launch(void* const* d_in, const int* in_sizes, int n_in,
                              void* d_out, int out_size, void* d_ws, size_t ws_size,
                              hipStream_t stream){
  (void)in_sizes; (void)n_in; (void)out_size;
  const float* h   = (const float*)d_in[0];
  const float* r   = (const float*)d_in[1];
  const float* adj = (const float*)d_in[2];
  const float* W   = (const float*)d_in[3];
  // d_in[4] = b_lin: unused (softmax shift invariance)

  float* hout = (float*)d_out;           // EN*DN
  float* rout = hout + EN*DN;            // RN*DN
  float* aout = rout + RN*DN;            // RN*EN

  // layout: s2 | lE | racc | lRg(xS) | sEg(xS) | alog   (lE,racc contiguous
  // for the zero sweep; lRg/sEg zero-free in SL mode: every slot written once)
  const size_t needSL = (size_t)(EN*RN + RN*DN*2 + 8*(size_t)SZE + EN*RN) * 4;
  const bool   SL     = ws_size >= needSL;
  const int    S      = SL ? 4 : 1;

  float* ws   = (float*)d_ws;
  float* s2   = ws;                  // EN*RN
  float* lE   = s2 + EN*RN;          // RN*DN  --+ zeroed by k_adj
  float* racc = lE + RN*DN;          // RN*DN  --+ (+ lRg/sEg too in legacy)
  float* lRg  = racc + RN*DN;        // S*EN*DN
  float* sEg  = lRg + (size_t)S*SZE; // S*EN*DN
  float* alog = sEg + (size_t)S*SZE; // EN*RN

  const int nf4 = SL ? (RN*DN*2)/4 : (RN*DN*2 + EN*DN*2)/4;

  k_adj<<<EN/4, 256, 0, stream>>>(adj, s2, (float4*)lE, nf4);
  if(SL){
    kA<true>   <<<GRIDAB,    256, 0, stream>>>(h, r, s2, lRg, lE);
    kB<true>   <<<GRIDAB,    256, 0, stream>>>(h, r, s2, lRg, lE, W, alog, racc, sEg);
    kTail<true><<<EN*DN/256, 256, 0, stream>>>(h, sEg, alog, r, racc, hout, rout, aout);
  } else {
    kA<false>   <<<GRIDAB,    256, 0, stream>>>(h, r, s2, lRg, lE);
    kB<false>   <<<GRIDAB,    256, 0, stream>>>(h, r, s2, lRg, lE, W, alog, racc, sEg);
    kTail<false><<<EN*DN/256, 256, 0, stream>>>(h, sEg, alog, r, racc, hout, rout, aout);
  }
}

// Round 14
// 160.085 us; speedup vs baseline: 1.2532x; 1.0036x over previous
//
#include <hip/hip_runtime.h>

// RelatEntAtt: E=4096, R=64, D=256. Fully fused recompute; att (E,R,D) never
// materialized. exp2 with log2(e) folded into the adj-softmax output.
// ---- session ledger ----
// R2 (180.9us): CH=8, JT=16, arrays SROA to regs.
// R3/R4/R10/R13 (FAILED perf): ANY change to private-array shapes / cross-loop
//     live state breaks SROA -> scratch (4 confirmations). CH=8 + JT=16 +
//     row16_sum immediate-consume DPP are load-bearing. HOT LOOPS FROZEN.
// R5/R6/R11/R14 (181/170.1/167.1/168.8us): j-quarter split, grid 2048.
// R7/R8/R9 (FAILED): cooperative launch incompatible; no spin barriers; atomic
//     results only consumable across a kernel boundary (cross-XCD visibility).
// R12 (170.1us): adj-fold into BOTH kA and kB = net loss; exposed atomic model
//     (WRITE_SIZE == atomic-lane-ops x 4B, ~0.9TB/s drain).
// R15 (160.7us, BEST): fanin-4 accumulators (lRg, sEg) -> per-quarter sliced
//     plain stores. kA faster + 33.5MB zeroing gone; kB flat (VALU-bound 41us,
//     atomics already overlapped). Wall-sum(kernels) ~42us = 3 gaps.
// R16: kill one gap. k_adj folded into kA ONLY (R10 already ran this exact
//     prologue+publish through kA correctly): kA computes adj-softmax for its
//     8 e-rows, keeps own quarter in LDS, publishes own s2g quarter (unique
//     owner) for kB. kB reads s2g across the kernel boundary as before ->
//     single source, no consistency risk. Residual zeroing (lE+racc, 131KB in
//     SL mode) via hipMemsetAsync. 4 dispatches + 0 memset -> 3 + 1 memset.

#define EN 4096
#define RN 64
#define DN 256
#define JT 16          // j-tile width (PROVEN SROA shape - do not change)
#define LOG2E 1.44269504088896340736f
#define CHA 8   // e's per block (PROVEN SROA shape - do not change)
#define CHB 8
#define GRIDAB ((EN/CHA)*4)            // 2048 blocks: (e-chunk, j-quarter)
#define SZE (EN*DN)                    // slice stride for lRg4/sEg4

__device__ __forceinline__ float ex2(float x){ return __builtin_amdgcn_exp2f(x); }
__device__ __forceinline__ float rcpf(float x){ return __builtin_amdgcn_rcpf(x); }

template<int CTRL>
__device__ __forceinline__ float dpp_add(float v){
  int m = __builtin_amdgcn_update_dpp(0, __float_as_int(v), CTRL, 0xf, 0xf, true);
  return v + __int_as_float(m);
}
// lane (i%16)==15 ends with the sum of its 16-lane row
__device__ __forceinline__ float row16_sum(float v){
  v = dpp_add<0x111>(v);
  v = dpp_add<0x112>(v);
  v = dpp_add<0x114>(v);
  v = dpp_add<0x118>(v);
  return v;
}

// ---- kA: adj-softmax prologue (publishes own s2g quarter) + first sweep ----
// block = (e-chunk, j-quarter): e0 = (bid>>2)*CHA, j0 = (bid&3)*16
// lRg: sliced plain store (SL) or atomic; lE: atomic (fanin 512).
template<bool SL>
__global__ __launch_bounds__(256,4) void kA(const float* __restrict__ h,
                                            const float* __restrict__ r,
                                            const float* __restrict__ adj,
                                            float* __restrict__ s2g,
                                            float* __restrict__ lRg,
                                            float* __restrict__ lE){
  const int d  = threadIdx.x;
  const int q  = blockIdx.x & 3;
  const int e0 = (blockIdx.x >> 2) * CHA;
  const int j0 = q * JT;

  // adj softmax for rows e0..e0+7: wave w handles rows w and w+4; lane = j
  // over the full 64-j row. Own quarter -> LDS + global (unique owner per
  // (row, quarter) -> race-free). kB consumes s2g across the kernel boundary.
  __shared__ float s2s[CHA*JT];            // 512 B
  {
    const int w = d >> 6, lane = d & 63;
    #pragma unroll
    for(int rr2 = 0; rr2 < 2; rr2++){
      const int row = rr2*4 + w;
      float a  = adj[(e0 + row)*RN + lane];
      float ev = ex2(a * LOG2E);
      float s  = ev;
      #pragma unroll
      for(int off = 32; off > 0; off >>= 1) s += __shfl_xor(s, off, 64);
      float val = ev * (LOG2E * rcpf(s));
      const unsigned lj = (unsigned)(lane - j0);
      if(lj < 16u){
        s2s[row*JT + (int)lj] = val;
        s2g[(e0 + row)*RN + j0 + (int)lj] = val;
      }
    }
  }
  __syncthreads();

  float lR[CHA];
  #pragma unroll
  for(int ee = 0; ee < CHA; ee++) lR[ee] = 0.f;

  float rcol[JT], lEacc[JT];
  #pragma unroll
  for(int jj = 0; jj < JT; jj++){ rcol[jj] = r[(j0+jj)*DN + d]; lEacc[jj] = 0.f; }
  #pragma unroll
  for(int ee = 0; ee < CHA; ee++){
    const float he = h[(e0+ee)*DN + d];
    #pragma unroll
    for(int jj = 0; jj < JT; jj++){
      float t  = s2s[ee*JT + jj] * he * rcol[jj];
      float ev = ex2(fmaxf(t, 0.2f*t));
      lR[ee]   += ev;
      lEacc[jj] += ev;
    }
  }
  #pragma unroll
  for(int jj = 0; jj < JT; jj++) atomicAdd(&lE[(j0+jj)*DN + d], lEacc[jj]);
  if constexpr(SL){
    #pragma unroll
    for(int ee = 0; ee < CHA; ee++) lRg[q*SZE + (e0+ee)*DN + d] = lR[ee];
  } else {
    #pragma unroll
    for(int ee = 0; ee < CHA; ee++) atomicAdd(&lRg[(e0+ee)*DN + d], lR[ee]);
  }
}

// ---- kB: main fused sweep over own j-quarter ----
// per (e,d): pR = ev/lR (att_R), pE = ev/lE (att_E)
//   sEg[e,d]: sliced store (or atomic)   (h' ELU in kTail)
//   r'[j,d] += pR                        16-reg acc, atomic flush
//   alog[e,j] = sum_d pR*W_d             row16 DPP + LDS partial combine
template<bool SL>
__global__ __launch_bounds__(256,4) void kB(const float* __restrict__ h,
                                            const float* __restrict__ r,
                                            const float* __restrict__ s2,
                                            const float* __restrict__ lRg,
                                            const float* __restrict__ lE,
                                            const float* __restrict__ W,
                                            float* __restrict__ alog,
                                            float* __restrict__ racc_g,
                                            float* __restrict__ sEg){
  const int tid  = threadIdx.x;            // = d
  const int lane = tid & 63;
  const int grp  = tid >> 4;               // 16 groups of 16 lanes
  const int q    = blockIdx.x & 3;
  const int e0   = (blockIdx.x >> 2) * CHB;
  const int j0   = q * JT;
  __shared__ float s2s[CHB*JT];            // 512 B
  __shared__ float apart[CHB*16*20];       // [ee][g][jj], jj stride 1, g stride 20 -> 10 KB
  if(tid < CHB*JT) s2s[tid] = s2[(e0 + (tid >> 4))*RN + j0 + (tid & 15)];
  __syncthreads();

  const float wd = W[tid];
  float sE[CHB];
  #pragma unroll
  for(int ee = 0; ee < CHB; ee++) sE[ee] = 0.f;

  float rcol[JT], ile[JT], rAcc[JT];
  #pragma unroll
  for(int jj = 0; jj < JT; jj++){
    const int j = j0 + jj;
    rcol[jj] = r[j*DN + tid];
    ile[jj]  = rcpf(lE[j*DN + tid]);
    rAcc[jj] = 0.f;
  }
  for(int ee = 0; ee < CHB; ee++){
    const int e = e0 + ee;
    const float he = h[e*DN + tid];
    float il;
    if constexpr(SL){
      const int i = e*DN + tid;
      il = rcpf(lRg[i] + lRg[SZE + i] + lRg[2*SZE + i] + lRg[3*SZE + i]);
    } else {
      il = rcpf(lRg[e*DN + tid]);
    }
    const float u  = il * wd;
    #pragma unroll
    for(int jg = 0; jg < JT/4; jg++){
      float4 st;
      #pragma unroll
      for(int jj4 = 0; jj4 < 4; jj4++){
        const int jj = jg*4 + jj4;
        float t  = s2s[ee*JT + jj] * he * rcol[jj];
        float ev = ex2(fmaxf(t, 0.2f*t));
        rAcc[jj] = fmaf(ev, il, rAcc[jj]);      // pR accumulated over e
        sE[ee]   = fmaf(ev, ile[jj], sE[ee]);   // pE sum over own j
        float rs = row16_sum(ev * u);           // alog contribution
        if(jj4==0) st.x = rs; else if(jj4==1) st.y = rs;
        else if(jj4==2) st.z = rs; else st.w = rs;
      }
      if((lane & 15) == 15){
        *reinterpret_cast<float4*>(&apart[(ee*16 + grp)*20 + jg*4]) = st;
      }
    }
  }
  __syncthreads();
  if(tid < CHB*JT){                        // 128 threads: ee = tid>>4, jj = tid&15
    const int ee = tid >> 4, jj = tid & 15;
    float sum = 0.f;
    #pragma unroll
    for(int g = 0; g < 16; g++) sum += apart[(ee*16 + g)*20 + jj];
    alog[(e0+ee)*RN + j0 + jj] = sum;
  }
  #pragma unroll
  for(int jj = 0; jj < JT; jj++) atomicAdd(&racc_g[(j0+jj)*DN + tid], rAcc[jj]);
  if constexpr(SL){
    #pragma unroll
    for(int ee = 0; ee < CHB; ee++) sEg[q*SZE + (e0+ee)*DN + tid] = sE[ee];
  } else {
    #pragma unroll
    for(int ee = 0; ee < CHB; ee++) atomicAdd(&sEg[(e0+ee)*DN + tid], sE[ee]);
  }
}

// ---- tail: hout = elu(h*sEg) everywhere; blocks 0..63 also do rout + alpha ----
// (reference's reshape(R,E,1)+softmax(axis=1) == per-row softmax on the e*64+j
//  flat array viewed as [64][4096]; b_lin dropped by shift invariance)
template<bool SL>
__global__ __launch_bounds__(256) void kTail(const float* __restrict__ h,
                                             const float* __restrict__ sEg,
                                             const float* __restrict__ alog,
                                             const float* __restrict__ r,
                                             const float* __restrict__ racc,
                                             float* __restrict__ hout,
                                             float* __restrict__ rout,
                                             float* __restrict__ aout){
  const int b = blockIdx.x, tid = threadIdx.x;
  {
    const int i = b*256 + tid;               // grid 4096 covers EN*DN
    float sv;
    if constexpr(SL) sv = sEg[i] + sEg[SZE + i] + sEg[2*SZE + i] + sEg[3*SZE + i];
    else             sv = sEg[i];
    float hp = h[i] * sv;
    hout[i] = hp > 0.f ? hp : (ex2(hp*LOG2E) - 1.0f);
  }
  if(b < RN){                                 // block-uniform branch
    const int i = b*DN + tid;
    float v = r[i] * racc[i];
    rout[i] = v > 0.f ? v : (ex2(v*LOG2E) - 1.0f);

    const float* __restrict__ row = alog + b*EN;
    float exv[16]; float s = 0.f;
    #pragma unroll
    for(int k = 0; k < 16; k++){
      float v2 = ex2(row[k*256 + tid] * LOG2E);
      exv[k] = v2; s += v2;
    }
    #pragma unroll
    for(int off = 32; off > 0; off >>= 1) s += __shfl_xor(s, off, 64);
    __shared__ float wsum[4];
    if((tid & 63) == 0) wsum[tid>>6] = s;
    __syncthreads();
    float inv = 1.0f / (wsum[0] + wsum[1] + wsum[2] + wsum[3]);
    float* __restrict__ orow = aout + b*EN;
    #pragma unroll
    for(int k = 0; k < 16; k++) orow[k*256 + tid] = exv[k] * inv;
  }
}

extern "C" void kernel_launch(void* const* d_in, const int* in_sizes, int n_in,
                              void* d_out, int out_size, void* d_ws, size_t ws_size,
                              hipStream_t stream){
  (void)in_sizes; (void)n_in; (void)out_size;
  const float* h   = (const float*)d_in[0];
  const float* r   = (const float*)d_in[1];
  const float* adj = (const float*)d_in[2];
  const float* W   = (const float*)d_in[3];
  // d_in[4] = b_lin: unused (softmax shift invariance)

  float* hout = (float*)d_out;           // EN*DN
  float* rout = hout + EN*DN;            // RN*DN
  float* aout = rout + RN*DN;            // RN*EN

  // layout: s2 | lE | racc | lRg(xS) | sEg(xS) | alog   (lE..sEg contiguous
  // so the non-SL fallback can zero them with one memset)
  const size_t needSL = (size_t)(EN*RN + RN*DN*2 + 8*(size_t)SZE + EN*RN) * 4;
  const bool   SL     = ws_size >= needSL;
  const int    S      = SL ? 4 : 1;

  float* ws   = (float*)d_ws;
  float* s2   = ws;                  // EN*RN   (written by kA, read by kB)
  float* lE   = s2 + EN*RN;          // RN*DN  --+ zeroed by memset
  float* racc = lE + RN*DN;          // RN*DN  --+ (+ lRg/sEg in non-SL)
  float* lRg  = racc + RN*DN;        // S*EN*DN
  float* sEg  = lRg + (size_t)S*SZE; // S*EN*DN
  float* alog = sEg + (size_t)S*SZE; // EN*RN

  const size_t zbytes = SL ? (size_t)(RN*DN*2)*4
                           : (size_t)(RN*DN*2 + EN*DN*2)*4;
  hipMemsetAsync(lE, 0, zbytes, stream);

  if(SL){
    kA<true>   <<<GRIDAB,    256, 0, stream>>>(h, r, adj, s2, lRg, lE);
    kB<true>   <<<GRIDAB,    256, 0, stream>>>(h, r, s2, lRg, lE, W, alog, racc, sEg);
    kTail<true><<<EN*DN/256, 256, 0, stream>>>(h, sEg, alog, r, racc, hout, rout, aout);
  } else {
    kA<false>   <<<GRIDAB,    256, 0, stream>>>(h, r, adj, s2, lRg, lE);
    kB<false>   <<<GRIDAB,    256, 0, stream>>>(h, r, s2, lRg, lE, W, alog, racc, sEg);
    kTail<false><<<EN*DN/256, 256, 0, stream>>>(h, sEg, alog, r, racc, hout, rout, aout);
  }
}